// Round 10
// baseline (226.629 us; speedup 1.0000x reference)
//
#include <hip/hip_runtime.h>
#include <stdint.h>

#define IN_C   128
#define OUT_C  128
#define KTOT   1152      // IN_C*3*3
#define NG     8
#define NW     8
#define NB     8
#define HH     56
#define WWID   56
#define NPIX   3136
#define PPAD   3200
#define MTOT   1024      // OUT_C*NW
#define HALO   58        // 56 + zero border on each side
#define HPIX   (HALO*HALO)   // 3364

// R10 = R9 resubmitted verbatim (R9 bench died on container acquisition, not
// on the kernel; audit found no hang/oob path). R4's gemm (79us, best
// verified: M-tile 64, grid 3200, pair-top VMEM clustering, afc/afn rotation)
// with s_kernel FUSED into the gemm epilogue: out = sum_j acc_j * s_j(p),
// s_j(p) = sum_g softmax(Alpha)[g,p] * rsh[g*8+j], rsh computed per-lane
// (one 128-dot) and gathered via __shfl -- ZERO extra LDS (preserves the
// 5 blocks/CU cap). Deletes the s_kernel launch + Sws round-trip.
// Lessons kept: no launch_bounds reg cap (R2/R5); B stays on cp16 path (R6);
// 16x16 shape + fine grid (R7/R8 regressions).

typedef __attribute__((ext_vector_type(8))) short short8;
typedef __attribute__((ext_vector_type(8))) unsigned short ushort8;
typedef __attribute__((ext_vector_type(4))) float f32x4;

__device__ __forceinline__ unsigned short f2bf(float f) {
    unsigned u = __float_as_uint(f);
    u += 0x7FFF + ((u >> 16) & 1);          // round-to-nearest-even
    return (unsigned short)(u >> 16);
}

__device__ __forceinline__ void cp16(const unsigned short* g, unsigned short* l) {
    __builtin_amdgcn_global_load_lds(
        (const __attribute__((address_space(1))) unsigned int*)g,
        (__attribute__((address_space(3))) unsigned int*)l,
        16, 0, 0);
}

// ---------- 1) fused prep: gap (0..1023) | tconv/pack (1024..1151) | transpose (1152..1375) ----------
__global__ __launch_bounds__(256) void prep_kernel(const float* __restrict__ in,
                                                   const float* __restrict__ T,
                                                   float* __restrict__ xse,
                                                   unsigned short* __restrict__ Apack,
                                                   unsigned short* __restrict__ Xt) {
    __shared__ __align__(16) unsigned char smem[32768];   // 32 KB
    const int blk = blockIdx.x;
    const int t = threadIdx.x;

    if (blk < 1024) {
        // ---- global average pool: xse[b,c] ----
        const float* src = in + (size_t)blk * NPIX;
        float s = 0.f;
        for (int i = t; i < NPIX / 4; i += 256) {
            float4 v = ((const float4*)src)[i];
            s += v.x + v.y + v.z + v.w;
        }
        #pragma unroll
        for (int off = 32; off; off >>= 1) s += __shfl_down(s, off);
        float* ws4 = (float*)smem;
        if ((t & 63) == 0) ws4[t >> 6] = s;
        __syncthreads();
        if (t == 0)
            xse[blk] = (ws4[0] + ws4[1] + ws4[2] + ws4[3]) * (1.0f / (float)NPIX);
        return;
    }
    if (blk < 1152) {
        // ---- tconv+pack: block per o. T[o][k][j] slab -> bf16 LDS (18 KB) ->
        //      fragment-linear Apack[m16][kt][lq][lr][8e].
        unsigned short* lh = (unsigned short*)smem;  // 9216 bf16 = 18 KB
        const int o = blk - 1024;
        const float* To = T + (size_t)o * 9216;
        #pragma unroll
        for (int it = 0; it < 9; it++) {
            const int f = it * 256 + t;              // 0..2303 float4 units
            const float4 v = ((const float4*)To)[f];
            ushort4 h;
            h.x = f2bf(v.x); h.y = f2bf(v.y); h.z = f2bf(v.z); h.w = f2bf(v.w);
            *(ushort4*)&lh[f * 4] = h;
        }
        __syncthreads();
        const int m16b = o >> 1;
        const int lrb = (o & 1) * 8;
        #pragma unroll
        for (int it = 0; it < 5; it++) {
            const int ch = it * 256 + t;             // 0..1151: ch = kc*8 + j
            if (ch < 1152) {
                const int j = ch & 7, kc = ch >> 3;  // kc = k-octet 0..143
                const int s = kc >> 4, c0 = (kc & 15) << 3;
                const int kt = kc >> 2, lq = kc & 3;
                ushort8 v;
                #pragma unroll
                for (int i = 0; i < 8; i++)
                    v[i] = lh[((c0 + i) * 9 + s) * 8 + j];
                const size_t off = ((((size_t)m16b * 36 + kt) * 4 + lq) * 16 + lrb + j) * 8;
                *(ushort8*)&Apack[off] = v;
            }
        }
        return;
    }
    // ---- transpose: in[b][c][y][x] fp32 -> Xt[b][(y+1)*58+(x+1)][c] bf16, zero halo ----
    unsigned short* tile = (unsigned short*)smem;    // 32 KB, [c][pix 0..112)
    const int idx = blk - 1152;                      // 0..223
    const int yt = idx % 28;
    const int b  = idx / 28;
    const int y0 = yt * 2;

    #pragma unroll
    for (int it = 0; it < 14; it++) {
        const int f = it * 256 + t;
        const int c = f / 28;
        const int rem = f - c * 28;
        const int y = rem / 14;
        const int x4 = rem - y * 14;
        const float4 v = *(const float4*)(in + ((size_t)(b * IN_C + c)) * NPIX
                                          + (y0 + y) * WWID + x4 * 4);
        unsigned short bf0 = f2bf(v.x), bf1 = f2bf(v.y), bf2 = f2bf(v.z), bf3 = f2bf(v.w);
        const int ppb = (y * WWID + x4 * 4) ^ (((c >> 3) & 15) << 2);
        uint2 pk;
        pk.x = (unsigned)bf0 | ((unsigned)bf1 << 16);
        pk.y = (unsigned)bf2 | ((unsigned)bf3 << 16);
        *(uint2*)&tile[c * 128 + ppb] = pk;
    }
    __syncthreads();

    #pragma unroll
    for (int it = 0; it < 7; it++) {
        const int ch = it * 256 + t;
        const int oct = ch & 15;
        const int pp = ch >> 4;
        const int sw = oct << 2;
        ushort8 v;
        #pragma unroll
        for (int i = 0; i < 8; i++)
            v[i] = tile[(oct * 8 + i) * 128 + (pp ^ sw)];
        const int y2 = (pp >= WWID) ? 1 : 0;
        const int xg = pp - y2 * WWID;
        const size_t hp = (size_t)b * HPIX + (y0 + y2 + 1) * HALO + (xg + 1);
        *(ushort8*)&Xt[hp * 128 + oct * 8] = v;
    }

    if (t < 64) {   // halo columns xx=0,57 for this block's two rows
        const int pi = t >> 4, oct = t & 15;
        const int yy = y0 + 1 + (pi >> 1);
        const int xx = (pi & 1) * 57;
        *(ushort8*)&Xt[((size_t)b * HPIX + yy * HALO + xx) * 128 + oct * 8] =
            (ushort8){0, 0, 0, 0, 0, 0, 0, 0};
    }
    if (yt == 0 || yt == 27) {   // halo rows yy=0 / 57
        const int yy = (yt == 0) ? 0 : 57;
        #pragma unroll
        for (int it = 0; it < 4; it++) {
            const int ch = it * 256 + t;
            if (ch < 928) {
                const int xx = ch >> 4, oct = ch & 15;
                *(ushort8*)&Xt[((size_t)b * HPIX + yy * HALO + xx) * 128 + oct * 8] =
                    (ushort8){0, 0, 0, 0, 0, 0, 0, 0};
            }
        }
    }
}

// ---------- 2) main GEMM + fused routing/blend epilogue ----------
// 36 BK=32 stages in 18 pairs (unrolled 2 pairs/iter): 4 B-buffers, one
// barrier per pair. ALL VMEM for pair p+1 (4 cp16 + 4 A-frag loads) issued at
// top of pair p (afc/afn rotation), sched_barrier(0) pins the cluster.
// M-tile = 64 rows, N-tile = 128 px. Grid 3200. Identical to the 79us R4
// kernel through the main loop; epilogue computes routing inline.
__global__ __launch_bounds__(256) void gemm_kernel(const unsigned short* __restrict__ Apack,
                                                   const unsigned short* __restrict__ Xt,
                                                   const float* __restrict__ Alpha,
                                                   const int* __restrict__ mask,
                                                   const float* __restrict__ xse,
                                                   const float* __restrict__ rw,
                                                   const float* __restrict__ rb,
                                                   const int* __restrict__ use_alpha,
                                                   const float* __restrict__ bias,
                                                   float* __restrict__ out) {
    __shared__ __align__(16) unsigned short Bsh[4][512 * 8];   // 4 x 8 KB
    const int tid = threadIdx.x;
    const int wv = tid >> 6, ln = tid & 63;
    const int lq = ln >> 4, lr = ln & 15;
    const int wrow = wv >> 1, wcol = wv & 1;

    const int lid = blockIdx.x;            // 0..3199
    const int b   = lid & 7;               // XCD = b
    const int sl  = lid >> 3;              // 0..399
    const int mt  = sl & 15;               // 16 M-tiles of 64 rows
    const int nt  = sl >> 4;               // 0..24

    f32x4 acc[2][4];
    #pragma unroll
    for (int i = 0; i < 2; i++)
        #pragma unroll
        for (int j = 0; j < 4; j++) acc[i][j] = (f32x4){0.f, 0.f, 0.f, 0.f};

    // B staging: chunk (r, slot js) holds octet q = js ^ (r&3) ^ ((r>>2)&3)
    const int js = tid & 3;
    const int r0 = tid >> 2,  q0 = js ^ (r0 & 3) ^ ((r0 >> 2) & 3);
    const int r1 = r0 + 64,   q1 = js ^ (r1 & 3) ^ ((r1 >> 2) & 3);
    const int p0 = min(nt * 128 + r0, NPIX - 1);
    const int p1 = min(nt * 128 + r1, NPIX - 1);
    const int y0p = p0 / WWID, x0p = p0 - y0p * WWID;
    const int y1p = p1 / WWID, x1p = p1 - y1p * WWID;
    const unsigned short* gb0 = Xt + ((size_t)b * HPIX + y0p * HALO + x0p) * 128 + q0 * 8;
    const unsigned short* gb1 = Xt + ((size_t)b * HPIX + y1p * HALO + x1p) * 128 + q1 * 8;
    unsigned short* lbA[4];   // per-buffer LDS target for chunk0 (chunk1 = +256*8)
    #pragma unroll
    for (int i = 0; i < 4; i++) lbA[i] = &Bsh[i][(wv * 64) * 8];

    // A fragment-linear bases: m16 = mt*4 + wrow*2 + tm, tm in 0..1
    const unsigned short* gaw[2];
    #pragma unroll
    for (int tm = 0; tm < 2; tm++) {
        const int m16 = mt * 4 + wrow * 2 + tm;
        gaw[tm] = Apack + ((size_t)m16 * 36 * 64 + ln) * 8;
    }

    // frag-read slot swizzle: j' = lq ^ (lr&3) ^ ((lr>>2)&3)
    const int jj = lq ^ (lr & 3) ^ ((lr >> 2) & 3);

    // prologue: tiles 0,1 -> buf0,buf1 (stage1 offB = 32); afc = stages 0,1
    cp16(gb0, lbA[0]); cp16(gb1, lbA[0] + 256 * 8);
    cp16(gb0 + 32, lbA[1]); cp16(gb1 + 32, lbA[1] + 256 * 8);
    short8 afc[2][2], afn[2][2];
    #pragma unroll
    for (int tm = 0; tm < 2; tm++) afc[0][tm] = *(const short8*)(gaw[tm]);
    #pragma unroll
    for (int tm = 0; tm < 2; tm++) afc[1][tm] = *(const short8*)(gaw[tm] + 512);

    #pragma unroll 1
    for (int it = 0; it < 9; it++) {
        // ================= pair 2*it (even): buffers 0,1; uses afc ===========
        __syncthreads();                   // stages 4it,4it+1 + afc ready
        {
            const int st2 = it * 4 + 2, st3 = it * 4 + 3;
            const int nk2 = st2 * 32, s2 = nk2 >> 7;
            const int kh2 = s2 / 3, kw2 = s2 - 3 * kh2;
            const int off2 = (kh2 * HALO + kw2) * 128 + (nk2 & 127);
            const int nk3 = st3 * 32, s3 = nk3 >> 7;
            const int kh3 = s3 / 3, kw3 = s3 - 3 * kh3;
            const int off3 = (kh3 * HALO + kw3) * 128 + (nk3 & 127);
            cp16(gb0 + off2, lbA[2]); cp16(gb1 + off2, lbA[2] + 256 * 8);
            cp16(gb0 + off3, lbA[3]); cp16(gb1 + off3, lbA[3] + 256 * 8);
            #pragma unroll
            for (int tm = 0; tm < 2; tm++)
                afn[0][tm] = *(const short8*)(gaw[tm] + (size_t)st2 * 512);
            #pragma unroll
            for (int tm = 0; tm < 2; tm++)
                afn[1][tm] = *(const short8*)(gaw[tm] + (size_t)st3 * 512);
            __builtin_amdgcn_sched_barrier(0);   // keep VMEM issue at pair-top

            // stage 4it: buffer 0, afc[0]
            {
                short8 bfr[4];
                #pragma unroll
                for (int tn = 0; tn < 4; tn++) {
                    const int row = wcol * 64 + tn * 16 + lr;
                    bfr[tn] = *(const short8*)&Bsh[0][(row * 4 + jj) * 8];
                }
                #pragma unroll
                for (int tm = 0; tm < 2; tm++)
                    #pragma unroll
                    for (int tn = 0; tn < 4; tn++)
                        acc[tm][tn] = __builtin_amdgcn_mfma_f32_16x16x32_bf16(
                            afc[0][tm], bfr[tn], acc[tm][tn], 0, 0, 0);
            }
            // stage 4it+1: buffer 1, afc[1]
            {
                short8 bfr[4];
                #pragma unroll
                for (int tn = 0; tn < 4; tn++) {
                    const int row = wcol * 64 + tn * 16 + lr;
                    bfr[tn] = *(const short8*)&Bsh[1][(row * 4 + jj) * 8];
                }
                #pragma unroll
                for (int tm = 0; tm < 2; tm++)
                    #pragma unroll
                    for (int tn = 0; tn < 4; tn++)
                        acc[tm][tn] = __builtin_amdgcn_mfma_f32_16x16x32_bf16(
                            afc[1][tm], bfr[tn], acc[tm][tn], 0, 0, 0);
            }
        }
        // ================= pair 2*it+1 (odd): buffers 2,3; uses afn ==========
        __syncthreads();                   // stages 4it+2,4it+3 + afn ready
        {
            if (it < 8) {
                const int st2 = it * 4 + 4, st3 = it * 4 + 5;
                const int nk2 = st2 * 32, s2 = nk2 >> 7;
                const int kh2 = s2 / 3, kw2 = s2 - 3 * kh2;
                const int off2 = (kh2 * HALO + kw2) * 128 + (nk2 & 127);
                const int nk3 = st3 * 32, s3 = nk3 >> 7;
                const int kh3 = s3 / 3, kw3 = s3 - 3 * kh3;
                const int off3 = (kh3 * HALO + kw3) * 128 + (nk3 & 127);
                cp16(gb0 + off2, lbA[0]); cp16(gb1 + off2, lbA[0] + 256 * 8);
                cp16(gb0 + off3, lbA[1]); cp16(gb1 + off3, lbA[1] + 256 * 8);
                #pragma unroll
                for (int tm = 0; tm < 2; tm++)
                    afc[0][tm] = *(const short8*)(gaw[tm] + (size_t)st2 * 512);
                #pragma unroll
                for (int tm = 0; tm < 2; tm++)
                    afc[1][tm] = *(const short8*)(gaw[tm] + (size_t)st3 * 512);
            }
            __builtin_amdgcn_sched_barrier(0);   // keep VMEM issue at pair-top

            // stage 4it+2: buffer 2, afn[0]
            {
                short8 bfr[4];
                #pragma unroll
                for (int tn = 0; tn < 4; tn++) {
                    const int row = wcol * 64 + tn * 16 + lr;
                    bfr[tn] = *(const short8*)&Bsh[2][(row * 4 + jj) * 8];
                }
                #pragma unroll
                for (int tm = 0; tm < 2; tm++)
                    #pragma unroll
                    for (int tn = 0; tn < 4; tn++)
                        acc[tm][tn] = __builtin_amdgcn_mfma_f32_16x16x32_bf16(
                            afn[0][tm], bfr[tn], acc[tm][tn], 0, 0, 0);
            }
            // stage 4it+3: buffer 3, afn[1]
            {
                short8 bfr[4];
                #pragma unroll
                for (int tn = 0; tn < 4; tn++) {
                    const int row = wcol * 64 + tn * 16 + lr;
                    bfr[tn] = *(const short8*)&Bsh[3][(row * 4 + jj) * 8];
                }
                #pragma unroll
                for (int tm = 0; tm < 2; tm++)
                    #pragma unroll
                    for (int tn = 0; tn < 4; tn++)
                        acc[tm][tn] = __builtin_amdgcn_mfma_f32_16x16x32_bf16(
                            afn[1][tm], bfr[tn], acc[tm][tn], 0, 0, 0);
            }
        }
    }

    // ---------- fused routing epilogue ----------
    // rsh[ln] = 0.25/(1+exp(-(rb[ln] + xse[b,:].rw[ln,:])))  (one lane each)
    float accr = rb[ln];
    {
        const float* xsb = xse + b * IN_C;
        const float* rwr = rw + ln * IN_C;
        #pragma unroll 8
        for (int c = 0; c < IN_C; c += 4) {
            const f32x4 xv = *(const f32x4*)&xsb[c];
            const f32x4 wv = *(const f32x4*)&rwr[c];
            accr += xv.x * wv.x + xv.y * wv.y + xv.z * wv.z + xv.w * wv.w;
        }
    }
    const float rln = 0.25f / (1.0f + expf(-accr));      // 2*sigmoid/8

    // per-pixel s_{j0..j0+3}(p) for this lane's 4 pixels; j0 = (lq&1)*4
    const int j0 = (lq & 1) * 4;
    const int ua = use_alpha[0];
    f32x4 sv[4];
    #pragma unroll
    for (int tn = 0; tn < 4; tn++) {
        const int p = nt * 128 + wcol * 64 + tn * 16 + lr;
        const int pS = min(p, NPIX - 1);
        float pr[8];
        if (ua) {
            float a[8], m = -1e30f;
            #pragma unroll
            for (int g = 0; g < 8; g++) {
                a[g] = Alpha[((size_t)(b * NG + g)) * NPIX + pS];
                m = fmaxf(m, a[g]);
            }
            float sum = 0.f;
            #pragma unroll
            for (int g = 0; g < 8; g++) { pr[g] = expf(a[g] - m); sum += pr[g]; }
            const float inv = 1.f / sum;
            #pragma unroll
            for (int g = 0; g < 8; g++) pr[g] *= inv;
        } else {
            const int mg = mask[(size_t)b * NPIX + pS];
            #pragma unroll
            for (int g = 0; g < 8; g++) pr[g] = (g == mg) ? 1.f : 0.f;
        }
        f32x4 sj = (f32x4){0.f, 0.f, 0.f, 0.f};
        #pragma unroll
        for (int g = 0; g < 8; g++) {
            const int base = g * 8 + j0;
            sj.x += pr[g] * __shfl(rln, base + 0);
            sj.y += pr[g] * __shfl(rln, base + 1);
            sj.z += pr[g] * __shfl(rln, base + 2);
            sj.w += pr[g] * __shfl(rln, base + 3);
        }
        sv[tn] = sj;
    }

    // blend + store: row r = m16*16 + lq*4 + reg -> o = m16*2 + (lq>>1)
    const int oo = lq >> 1;
    #pragma unroll
    for (int tm = 0; tm < 2; tm++) {
        const int o = mt * 8 + wrow * 4 + tm * 2 + oo;
        const float bo = bias[o];
        #pragma unroll
        for (int tn = 0; tn < 4; tn++) {
            const int p = nt * 128 + wcol * 64 + tn * 16 + lr;
            const f32x4 a = acc[tm][tn];
            const f32x4 s = sv[tn];
            float part = a.x * s.x + a.y * s.y + a.z * s.z + a.w * s.w;
            float tot = part + __shfl_xor(part, 16);
            if ((lq & 1) == 0 && p < NPIX)
                out[((size_t)b * OUT_C + o) * NPIX + p] = tot + bo;
        }
    }
}

extern "C" void kernel_launch(void* const* d_in, const int* in_sizes, int n_in,
                              void* d_out, int out_size, void* d_ws, size_t ws_size,
                              hipStream_t stream) {
    const float* inputs = (const float*)d_in[0];
    const int*   mask   = (const int*)d_in[1];
    const float* Alpha  = (const float*)d_in[2];
    const float* wtmpl  = (const float*)d_in[3];
    const float* rw     = (const float*)d_in[4];
    const float* rb     = (const float*)d_in[5];
    const float* bias   = (const float*)d_in[6];
    const int*   ua     = (const int*)d_in[7];
    float* out = (float*)d_out;

    char* ws = (char*)d_ws;
    unsigned short* Xt  = (unsigned short*)ws;                  // 8*3364*128*2 = 6,889,472
    unsigned short* Apk = (unsigned short*)(ws + 6889472);      // 1024*1152*2  = 2,359,296
    float*          xse = (float*)(ws + 10067968);              // 1024*4

    prep_kernel<<<1376, 256, 0, stream>>>(inputs, wtmpl, xse, Apk, Xt);
    gemm_kernel<<<3200, 256, 0, stream>>>(Apk, Xt, Alpha, mask, xse, rw, rb, ua, bias, out);
}

// Round 11
// 185.374 us; speedup vs baseline: 1.2226x; 1.2226x over previous
//
#include <hip/hip_runtime.h>
#include <stdint.h>

#define IN_C   128
#define OUT_C  128
#define KTOT   1152      // IN_C*3*3
#define NG     8
#define NW     8
#define NB     8
#define HH     56
#define WWID   56
#define NPIX   3136
#define PPAD   3200
#define MTOT   1024      // OUT_C*NW
#define HALO   58        // 56 + zero border on each side
#define HPIX   (HALO*HALO)   // 3364

// R11: R9/R10's fusion (s_kernel folded into gemm epilogue; non-gemm 82->59us
// verified) with the epilogue re-engineered for LOW VGPR. R10's failure mode:
// per-lane rw-row dot + 128 shfls pushed VGPR 60->128 -> occupancy 36->21% ->
// pair-drain stall tripled (gemm 79->167us). Fix: (1) rsh computed
// cooperatively (thread tid: quarter tid&3 of neuron tid>>2, coalesced f32x4
// rw reads, 2x shfl_xor fold) into REUSED Bsh LDS (zero extra LDS, preserves
// the 5 blocks/CU cap); (2) blend reads rsh via broadcast ds_read_b128 per
// (g,j0) -- no rv/sv register banks, transient pr[8]+sj only.
// Main loop + staging byte-identical to R4 (79us best). Numerics of the
// fused routing already harness-verified by R10 (passed, absmax unchanged).
// Lessons: no launch_bounds reg cap (R2/R5); B on cp16 path (R6); 16x16 +
// fine grid (R7/R8); epilogue VGPR <= ~100 or occupancy cliff (R10).

typedef __attribute__((ext_vector_type(8))) short short8;
typedef __attribute__((ext_vector_type(8))) unsigned short ushort8;
typedef __attribute__((ext_vector_type(4))) float f32x4;

__device__ __forceinline__ unsigned short f2bf(float f) {
    unsigned u = __float_as_uint(f);
    u += 0x7FFF + ((u >> 16) & 1);          // round-to-nearest-even
    return (unsigned short)(u >> 16);
}

__device__ __forceinline__ void cp16(const unsigned short* g, unsigned short* l) {
    __builtin_amdgcn_global_load_lds(
        (const __attribute__((address_space(1))) unsigned int*)g,
        (__attribute__((address_space(3))) unsigned int*)l,
        16, 0, 0);
}

// ---------- 1) fused prep: gap (0..1023) | tconv/pack (1024..1151) | transpose (1152..1375) ----------
__global__ __launch_bounds__(256) void prep_kernel(const float* __restrict__ in,
                                                   const float* __restrict__ T,
                                                   float* __restrict__ xse,
                                                   unsigned short* __restrict__ Apack,
                                                   unsigned short* __restrict__ Xt) {
    __shared__ __align__(16) unsigned char smem[32768];   // 32 KB
    const int blk = blockIdx.x;
    const int t = threadIdx.x;

    if (blk < 1024) {
        // ---- global average pool: xse[b,c] ----
        const float* src = in + (size_t)blk * NPIX;
        float s = 0.f;
        for (int i = t; i < NPIX / 4; i += 256) {
            float4 v = ((const float4*)src)[i];
            s += v.x + v.y + v.z + v.w;
        }
        #pragma unroll
        for (int off = 32; off; off >>= 1) s += __shfl_down(s, off);
        float* ws4 = (float*)smem;
        if ((t & 63) == 0) ws4[t >> 6] = s;
        __syncthreads();
        if (t == 0)
            xse[blk] = (ws4[0] + ws4[1] + ws4[2] + ws4[3]) * (1.0f / (float)NPIX);
        return;
    }
    if (blk < 1152) {
        // ---- tconv+pack: block per o. T[o][k][j] slab -> bf16 LDS (18 KB) ->
        //      fragment-linear Apack[m16][kt][lq][lr][8e].
        unsigned short* lh = (unsigned short*)smem;  // 9216 bf16 = 18 KB
        const int o = blk - 1024;
        const float* To = T + (size_t)o * 9216;
        #pragma unroll
        for (int it = 0; it < 9; it++) {
            const int f = it * 256 + t;              // 0..2303 float4 units
            const float4 v = ((const float4*)To)[f];
            ushort4 h;
            h.x = f2bf(v.x); h.y = f2bf(v.y); h.z = f2bf(v.z); h.w = f2bf(v.w);
            *(ushort4*)&lh[f * 4] = h;
        }
        __syncthreads();
        const int m16b = o >> 1;
        const int lrb = (o & 1) * 8;
        #pragma unroll
        for (int it = 0; it < 5; it++) {
            const int ch = it * 256 + t;             // 0..1151: ch = kc*8 + j
            if (ch < 1152) {
                const int j = ch & 7, kc = ch >> 3;  // kc = k-octet 0..143
                const int s = kc >> 4, c0 = (kc & 15) << 3;
                const int kt = kc >> 2, lq = kc & 3;
                ushort8 v;
                #pragma unroll
                for (int i = 0; i < 8; i++)
                    v[i] = lh[((c0 + i) * 9 + s) * 8 + j];
                const size_t off = ((((size_t)m16b * 36 + kt) * 4 + lq) * 16 + lrb + j) * 8;
                *(ushort8*)&Apack[off] = v;
            }
        }
        return;
    }
    // ---- transpose: in[b][c][y][x] fp32 -> Xt[b][(y+1)*58+(x+1)][c] bf16, zero halo ----
    unsigned short* tile = (unsigned short*)smem;    // 32 KB, [c][pix 0..112)
    const int idx = blk - 1152;                      // 0..223
    const int yt = idx % 28;
    const int b  = idx / 28;
    const int y0 = yt * 2;

    #pragma unroll
    for (int it = 0; it < 14; it++) {
        const int f = it * 256 + t;
        const int c = f / 28;
        const int rem = f - c * 28;
        const int y = rem / 14;
        const int x4 = rem - y * 14;
        const float4 v = *(const float4*)(in + ((size_t)(b * IN_C + c)) * NPIX
                                          + (y0 + y) * WWID + x4 * 4);
        unsigned short bf0 = f2bf(v.x), bf1 = f2bf(v.y), bf2 = f2bf(v.z), bf3 = f2bf(v.w);
        const int ppb = (y * WWID + x4 * 4) ^ (((c >> 3) & 15) << 2);
        uint2 pk;
        pk.x = (unsigned)bf0 | ((unsigned)bf1 << 16);
        pk.y = (unsigned)bf2 | ((unsigned)bf3 << 16);
        *(uint2*)&tile[c * 128 + ppb] = pk;
    }
    __syncthreads();

    #pragma unroll
    for (int it = 0; it < 7; it++) {
        const int ch = it * 256 + t;
        const int oct = ch & 15;
        const int pp = ch >> 4;
        const int sw = oct << 2;
        ushort8 v;
        #pragma unroll
        for (int i = 0; i < 8; i++)
            v[i] = tile[(oct * 8 + i) * 128 + (pp ^ sw)];
        const int y2 = (pp >= WWID) ? 1 : 0;
        const int xg = pp - y2 * WWID;
        const size_t hp = (size_t)b * HPIX + (y0 + y2 + 1) * HALO + (xg + 1);
        *(ushort8*)&Xt[hp * 128 + oct * 8] = v;
    }

    if (t < 64) {   // halo columns xx=0,57 for this block's two rows
        const int pi = t >> 4, oct = t & 15;
        const int yy = y0 + 1 + (pi >> 1);
        const int xx = (pi & 1) * 57;
        *(ushort8*)&Xt[((size_t)b * HPIX + yy * HALO + xx) * 128 + oct * 8] =
            (ushort8){0, 0, 0, 0, 0, 0, 0, 0};
    }
    if (yt == 0 || yt == 27) {   // halo rows yy=0 / 57
        const int yy = (yt == 0) ? 0 : 57;
        #pragma unroll
        for (int it = 0; it < 4; it++) {
            const int ch = it * 256 + t;
            if (ch < 928) {
                const int xx = ch >> 4, oct = ch & 15;
                *(ushort8*)&Xt[((size_t)b * HPIX + yy * HALO + xx) * 128 + oct * 8] =
                    (ushort8){0, 0, 0, 0, 0, 0, 0, 0};
            }
        }
    }
}

// ---------- 2) main GEMM + fused routing/blend epilogue ----------
// Main loop identical to R4 (79us): 36 BK=32 stages in 18 pairs, 4 B-buffers,
// one barrier per pair, ALL VMEM for pair p+1 at pair-top (afc/afn rotation).
// Epilogue: cooperative rsh -> Bsh-reuse LDS -> broadcast ds_read blend.
__global__ __launch_bounds__(256) void gemm_kernel(const unsigned short* __restrict__ Apack,
                                                   const unsigned short* __restrict__ Xt,
                                                   const float* __restrict__ Alpha,
                                                   const int* __restrict__ mask,
                                                   const float* __restrict__ xse,
                                                   const float* __restrict__ rw,
                                                   const float* __restrict__ rb,
                                                   const int* __restrict__ use_alpha,
                                                   const float* __restrict__ bias,
                                                   float* __restrict__ out) {
    __shared__ __align__(16) unsigned short Bsh[4][512 * 8];   // 4 x 8 KB
    const int tid = threadIdx.x;
    const int wv = tid >> 6, ln = tid & 63;
    const int lq = ln >> 4, lr = ln & 15;
    const int wrow = wv >> 1, wcol = wv & 1;

    const int lid = blockIdx.x;            // 0..3199
    const int b   = lid & 7;               // XCD = b
    const int sl  = lid >> 3;              // 0..399
    const int mt  = sl & 15;               // 16 M-tiles of 64 rows
    const int nt  = sl >> 4;               // 0..24

    f32x4 acc[2][4];
    #pragma unroll
    for (int i = 0; i < 2; i++)
        #pragma unroll
        for (int j = 0; j < 4; j++) acc[i][j] = (f32x4){0.f, 0.f, 0.f, 0.f};

    // B staging: chunk (r, slot js) holds octet q = js ^ (r&3) ^ ((r>>2)&3)
    const int js = tid & 3;
    const int r0 = tid >> 2,  q0 = js ^ (r0 & 3) ^ ((r0 >> 2) & 3);
    const int r1 = r0 + 64,   q1 = js ^ (r1 & 3) ^ ((r1 >> 2) & 3);
    const int p0 = min(nt * 128 + r0, NPIX - 1);
    const int p1 = min(nt * 128 + r1, NPIX - 1);
    const int y0p = p0 / WWID, x0p = p0 - y0p * WWID;
    const int y1p = p1 / WWID, x1p = p1 - y1p * WWID;
    const unsigned short* gb0 = Xt + ((size_t)b * HPIX + y0p * HALO + x0p) * 128 + q0 * 8;
    const unsigned short* gb1 = Xt + ((size_t)b * HPIX + y1p * HALO + x1p) * 128 + q1 * 8;
    unsigned short* lbA[4];   // per-buffer LDS target for chunk0 (chunk1 = +256*8)
    #pragma unroll
    for (int i = 0; i < 4; i++) lbA[i] = &Bsh[i][(wv * 64) * 8];

    // A fragment-linear bases: m16 = mt*4 + wrow*2 + tm, tm in 0..1
    const unsigned short* gaw[2];
    #pragma unroll
    for (int tm = 0; tm < 2; tm++) {
        const int m16 = mt * 4 + wrow * 2 + tm;
        gaw[tm] = Apack + ((size_t)m16 * 36 * 64 + ln) * 8;
    }

    // frag-read slot swizzle: j' = lq ^ (lr&3) ^ ((lr>>2)&3)
    const int jj = lq ^ (lr & 3) ^ ((lr >> 2) & 3);

    // prologue: tiles 0,1 -> buf0,buf1 (stage1 offB = 32); afc = stages 0,1
    cp16(gb0, lbA[0]); cp16(gb1, lbA[0] + 256 * 8);
    cp16(gb0 + 32, lbA[1]); cp16(gb1 + 32, lbA[1] + 256 * 8);
    short8 afc[2][2], afn[2][2];
    #pragma unroll
    for (int tm = 0; tm < 2; tm++) afc[0][tm] = *(const short8*)(gaw[tm]);
    #pragma unroll
    for (int tm = 0; tm < 2; tm++) afc[1][tm] = *(const short8*)(gaw[tm] + 512);

    #pragma unroll 1
    for (int it = 0; it < 9; it++) {
        // ================= pair 2*it (even): buffers 0,1; uses afc ===========
        __syncthreads();                   // stages 4it,4it+1 + afc ready
        {
            const int st2 = it * 4 + 2, st3 = it * 4 + 3;
            const int nk2 = st2 * 32, s2 = nk2 >> 7;
            const int kh2 = s2 / 3, kw2 = s2 - 3 * kh2;
            const int off2 = (kh2 * HALO + kw2) * 128 + (nk2 & 127);
            const int nk3 = st3 * 32, s3 = nk3 >> 7;
            const int kh3 = s3 / 3, kw3 = s3 - 3 * kh3;
            const int off3 = (kh3 * HALO + kw3) * 128 + (nk3 & 127);
            cp16(gb0 + off2, lbA[2]); cp16(gb1 + off2, lbA[2] + 256 * 8);
            cp16(gb0 + off3, lbA[3]); cp16(gb1 + off3, lbA[3] + 256 * 8);
            #pragma unroll
            for (int tm = 0; tm < 2; tm++)
                afn[0][tm] = *(const short8*)(gaw[tm] + (size_t)st2 * 512);
            #pragma unroll
            for (int tm = 0; tm < 2; tm++)
                afn[1][tm] = *(const short8*)(gaw[tm] + (size_t)st3 * 512);
            __builtin_amdgcn_sched_barrier(0);   // keep VMEM issue at pair-top

            // stage 4it: buffer 0, afc[0]
            {
                short8 bfr[4];
                #pragma unroll
                for (int tn = 0; tn < 4; tn++) {
                    const int row = wcol * 64 + tn * 16 + lr;
                    bfr[tn] = *(const short8*)&Bsh[0][(row * 4 + jj) * 8];
                }
                #pragma unroll
                for (int tm = 0; tm < 2; tm++)
                    #pragma unroll
                    for (int tn = 0; tn < 4; tn++)
                        acc[tm][tn] = __builtin_amdgcn_mfma_f32_16x16x32_bf16(
                            afc[0][tm], bfr[tn], acc[tm][tn], 0, 0, 0);
            }
            // stage 4it+1: buffer 1, afc[1]
            {
                short8 bfr[4];
                #pragma unroll
                for (int tn = 0; tn < 4; tn++) {
                    const int row = wcol * 64 + tn * 16 + lr;
                    bfr[tn] = *(const short8*)&Bsh[1][(row * 4 + jj) * 8];
                }
                #pragma unroll
                for (int tm = 0; tm < 2; tm++)
                    #pragma unroll
                    for (int tn = 0; tn < 4; tn++)
                        acc[tm][tn] = __builtin_amdgcn_mfma_f32_16x16x32_bf16(
                            afc[1][tm], bfr[tn], acc[tm][tn], 0, 0, 0);
            }
        }
        // ================= pair 2*it+1 (odd): buffers 2,3; uses afn ==========
        __syncthreads();                   // stages 4it+2,4it+3 + afn ready
        {
            if (it < 8) {
                const int st2 = it * 4 + 4, st3 = it * 4 + 5;
                const int nk2 = st2 * 32, s2 = nk2 >> 7;
                const int kh2 = s2 / 3, kw2 = s2 - 3 * kh2;
                const int off2 = (kh2 * HALO + kw2) * 128 + (nk2 & 127);
                const int nk3 = st3 * 32, s3 = nk3 >> 7;
                const int kh3 = s3 / 3, kw3 = s3 - 3 * kh3;
                const int off3 = (kh3 * HALO + kw3) * 128 + (nk3 & 127);
                cp16(gb0 + off2, lbA[0]); cp16(gb1 + off2, lbA[0] + 256 * 8);
                cp16(gb0 + off3, lbA[1]); cp16(gb1 + off3, lbA[1] + 256 * 8);
                #pragma unroll
                for (int tm = 0; tm < 2; tm++)
                    afc[0][tm] = *(const short8*)(gaw[tm] + (size_t)st2 * 512);
                #pragma unroll
                for (int tm = 0; tm < 2; tm++)
                    afc[1][tm] = *(const short8*)(gaw[tm] + (size_t)st3 * 512);
            }
            __builtin_amdgcn_sched_barrier(0);   // keep VMEM issue at pair-top

            // stage 4it+2: buffer 2, afn[0]
            {
                short8 bfr[4];
                #pragma unroll
                for (int tn = 0; tn < 4; tn++) {
                    const int row = wcol * 64 + tn * 16 + lr;
                    bfr[tn] = *(const short8*)&Bsh[2][(row * 4 + jj) * 8];
                }
                #pragma unroll
                for (int tm = 0; tm < 2; tm++)
                    #pragma unroll
                    for (int tn = 0; tn < 4; tn++)
                        acc[tm][tn] = __builtin_amdgcn_mfma_f32_16x16x32_bf16(
                            afn[0][tm], bfr[tn], acc[tm][tn], 0, 0, 0);
            }
            // stage 4it+3: buffer 3, afn[1]
            {
                short8 bfr[4];
                #pragma unroll
                for (int tn = 0; tn < 4; tn++) {
                    const int row = wcol * 64 + tn * 16 + lr;
                    bfr[tn] = *(const short8*)&Bsh[3][(row * 4 + jj) * 8];
                }
                #pragma unroll
                for (int tm = 0; tm < 2; tm++)
                    #pragma unroll
                    for (int tn = 0; tn < 4; tn++)
                        acc[tm][tn] = __builtin_amdgcn_mfma_f32_16x16x32_bf16(
                            afn[1][tm], bfr[tn], acc[tm][tn], 0, 0, 0);
            }
        }
    }

    // ---------- fused routing epilogue (low-VGPR) ----------
    // rsh[t] = 0.25/(1+exp(-(rb[t] + xse[b,:].rw[t,:]))), computed
    // cooperatively: thread tid handles quarter (tid&3) of neuron (tid>>2),
    // coalesced f32x4 rw reads, 2x shfl_xor fold, write into reused Bsh LDS.
    __syncthreads();                       // all waves done with Bsh
    float* rshL = (float*)&Bsh[0][0];      // 64 floats (256 B) reuse
    {
        const int tq = tid >> 2, qq = tid & 3;
        const float* rwr = rw + tq * IN_C + qq * 32;
        const float* xsb = xse + b * IN_C + qq * 32;
        float partial = 0.f;
        #pragma unroll
        for (int c = 0; c < 32; c += 4) {
            const f32x4 wvv = *(const f32x4*)&rwr[c];
            const f32x4 xvv = *(const f32x4*)&xsb[c];
            partial += xvv.x * wvv.x + xvv.y * wvv.y + xvv.z * wvv.z + xvv.w * wvv.w;
        }
        partial += __shfl_xor(partial, 1);
        partial += __shfl_xor(partial, 2);
        if (qq == 0)
            rshL[tq] = 0.25f / (1.0f + expf(-(partial + rb[tq])));   // 2*sigmoid/8
    }
    __syncthreads();                       // rshL visible to all

    // per-pixel softmax + blend + store; j0 = (lq&1)*4, o = mt*8+wrow*4+tm*2+(lq>>1)
    const int j0 = (lq & 1) * 4;
    const int oo = lq >> 1;
    const int ua = use_alpha[0];
    #pragma unroll
    for (int tn = 0; tn < 4; tn++) {
        const int p = nt * 128 + wcol * 64 + tn * 16 + lr;
        const int pS = min(p, NPIX - 1);
        float pr[8];
        if (ua) {
            float m = -1e30f;
            #pragma unroll
            for (int g = 0; g < 8; g++) {
                pr[g] = Alpha[((size_t)(b * NG + g)) * NPIX + pS];
                m = fmaxf(m, pr[g]);
            }
            float sum = 0.f;
            #pragma unroll
            for (int g = 0; g < 8; g++) { pr[g] = expf(pr[g] - m); sum += pr[g]; }
            const float inv = 1.f / sum;
            #pragma unroll
            for (int g = 0; g < 8; g++) pr[g] *= inv;
        } else {
            const int mg = mask[(size_t)b * NPIX + pS];
            #pragma unroll
            for (int g = 0; g < 8; g++) pr[g] = (g == mg) ? 1.f : 0.f;
        }
        f32x4 sj = (f32x4){0.f, 0.f, 0.f, 0.f};
        #pragma unroll
        for (int g = 0; g < 8; g++) {      // broadcast ds_read_b128, conflict-free
            const f32x4 rv = *(const f32x4*)&rshL[g * 8 + j0];
            sj.x += pr[g] * rv.x;
            sj.y += pr[g] * rv.y;
            sj.z += pr[g] * rv.z;
            sj.w += pr[g] * rv.w;
        }
        #pragma unroll
        for (int tm = 0; tm < 2; tm++) {
            const int o = mt * 8 + wrow * 4 + tm * 2 + oo;
            const f32x4 a = acc[tm][tn];
            float part = a.x * sj.x + a.y * sj.y + a.z * sj.z + a.w * sj.w;
            float tot = part + __shfl_xor(part, 16);
            if ((lq & 1) == 0 && p < NPIX)
                out[((size_t)b * OUT_C + o) * NPIX + p] = tot + bias[o];
        }
    }
}

extern "C" void kernel_launch(void* const* d_in, const int* in_sizes, int n_in,
                              void* d_out, int out_size, void* d_ws, size_t ws_size,
                              hipStream_t stream) {
    const float* inputs = (const float*)d_in[0];
    const int*   mask   = (const int*)d_in[1];
    const float* Alpha  = (const float*)d_in[2];
    const float* wtmpl  = (const float*)d_in[3];
    const float* rw     = (const float*)d_in[4];
    const float* rb     = (const float*)d_in[5];
    const float* bias   = (const float*)d_in[6];
    const int*   ua     = (const int*)d_in[7];
    float* out = (float*)d_out;

    char* ws = (char*)d_ws;
    unsigned short* Xt  = (unsigned short*)ws;                  // 8*3364*128*2 = 6,889,472
    unsigned short* Apk = (unsigned short*)(ws + 6889472);      // 1024*1152*2  = 2,359,296
    float*          xse = (float*)(ws + 10067968);              // 1024*4

    prep_kernel<<<1376, 256, 0, stream>>>(inputs, wtmpl, xse, Apk, Xt);
    gemm_kernel<<<3200, 256, 0, stream>>>(Apk, Xt, Alpha, mask, xse, rw, rb, ua, bias, out);
}

// Round 12
// 174.505 us; speedup vs baseline: 1.2987x; 1.0623x over previous
//
#include <hip/hip_runtime.h>
#include <stdint.h>

#define IN_C   128
#define OUT_C  128
#define KTOT   1152      // IN_C*3*3
#define NG     8
#define NW     8
#define NB     8
#define HH     56
#define WWID   56
#define NPIX   3136
#define PPAD   3200
#define MTOT   1024      // OUT_C*NW
#define HALO   58        // 56 + zero border on each side
#define HPIX   (HALO*HALO)   // 3364

// R12: factored fusion. R11 showed the fused epilogue's cost is the 128x
// redundant per-pixel softmax (26M expf vs s_kernel's 213K; VALU +18us,
// stall +18us). Fix: probs = softmax(Alpha) (xse-INDEPENDENT) computed once
// per pixel in prep (+104 blocks) -> Pws[b][p][8]; gemm epilogue keeps only
// R11's cheap cooperative rsh (Bsh-reuse LDS) and a branch-free blend:
// 2 coalesced f32x4 Pws loads/px + 8 broadcast LDS reads + 32 FMA.
// Main GEMM loop byte-identical to R4 (79us best). Launch-boundary saving
// of the fusion retained (s_kernel deleted).
// Lessons: no launch_bounds reg cap (R2/R5); B on cp16 path (R6); 16x16 +
// fine grid (R7/R8); epilogue must be low-VGPR (R10) AND low-redundancy (R11).

typedef __attribute__((ext_vector_type(8))) short short8;
typedef __attribute__((ext_vector_type(8))) unsigned short ushort8;
typedef __attribute__((ext_vector_type(4))) float f32x4;

__device__ __forceinline__ unsigned short f2bf(float f) {
    unsigned u = __float_as_uint(f);
    u += 0x7FFF + ((u >> 16) & 1);          // round-to-nearest-even
    return (unsigned short)(u >> 16);
}

__device__ __forceinline__ void cp16(const unsigned short* g, unsigned short* l) {
    __builtin_amdgcn_global_load_lds(
        (const __attribute__((address_space(1))) unsigned int*)g,
        (__attribute__((address_space(3))) unsigned int*)l,
        16, 0, 0);
}

// ---------- 1) fused prep: gap (0..1023) | tconv/pack (1024..1151) |
//             transpose (1152..1375) | probs (1376..1479) ----------
__global__ __launch_bounds__(256) void prep_kernel(const float* __restrict__ in,
                                                   const float* __restrict__ T,
                                                   const float* __restrict__ Alpha,
                                                   const int* __restrict__ mask,
                                                   const int* __restrict__ use_alpha,
                                                   float* __restrict__ xse,
                                                   unsigned short* __restrict__ Apack,
                                                   unsigned short* __restrict__ Xt,
                                                   float* __restrict__ Pws) {
    __shared__ __align__(16) unsigned char smem[32768];   // 32 KB
    const int blk = blockIdx.x;
    const int t = threadIdx.x;

    if (blk < 1024) {
        // ---- global average pool: xse[b,c] ----
        const float* src = in + (size_t)blk * NPIX;
        float s = 0.f;
        for (int i = t; i < NPIX / 4; i += 256) {
            float4 v = ((const float4*)src)[i];
            s += v.x + v.y + v.z + v.w;
        }
        #pragma unroll
        for (int off = 32; off; off >>= 1) s += __shfl_down(s, off);
        float* ws4 = (float*)smem;
        if ((t & 63) == 0) ws4[t >> 6] = s;
        __syncthreads();
        if (t == 0)
            xse[blk] = (ws4[0] + ws4[1] + ws4[2] + ws4[3]) * (1.0f / (float)NPIX);
        return;
    }
    if (blk < 1152) {
        // ---- tconv+pack: block per o. T[o][k][j] slab -> bf16 LDS (18 KB) ->
        //      fragment-linear Apack[m16][kt][lq][lr][8e].
        unsigned short* lh = (unsigned short*)smem;  // 9216 bf16 = 18 KB
        const int o = blk - 1024;
        const float* To = T + (size_t)o * 9216;
        #pragma unroll
        for (int it = 0; it < 9; it++) {
            const int f = it * 256 + t;              // 0..2303 float4 units
            const float4 v = ((const float4*)To)[f];
            ushort4 h;
            h.x = f2bf(v.x); h.y = f2bf(v.y); h.z = f2bf(v.z); h.w = f2bf(v.w);
            *(ushort4*)&lh[f * 4] = h;
        }
        __syncthreads();
        const int m16b = o >> 1;
        const int lrb = (o & 1) * 8;
        #pragma unroll
        for (int it = 0; it < 5; it++) {
            const int ch = it * 256 + t;             // 0..1151: ch = kc*8 + j
            if (ch < 1152) {
                const int j = ch & 7, kc = ch >> 3;  // kc = k-octet 0..143
                const int s = kc >> 4, c0 = (kc & 15) << 3;
                const int kt = kc >> 2, lq = kc & 3;
                ushort8 v;
                #pragma unroll
                for (int i = 0; i < 8; i++)
                    v[i] = lh[((c0 + i) * 9 + s) * 8 + j];
                const size_t off = ((((size_t)m16b * 36 + kt) * 4 + lq) * 16 + lrb + j) * 8;
                *(ushort8*)&Apack[off] = v;
            }
        }
        return;
    }
    if (blk < 1376) {
        // ---- transpose: in[b][c][y][x] fp32 -> Xt[b][(y+1)*58+(x+1)][c] bf16, zero halo ----
        unsigned short* tile = (unsigned short*)smem;    // 32 KB, [c][pix 0..112)
        const int idx = blk - 1152;                      // 0..223
        const int yt = idx % 28;
        const int b  = idx / 28;
        const int y0 = yt * 2;

        #pragma unroll
        for (int it = 0; it < 14; it++) {
            const int f = it * 256 + t;
            const int c = f / 28;
            const int rem = f - c * 28;
            const int y = rem / 14;
            const int x4 = rem - y * 14;
            const float4 v = *(const float4*)(in + ((size_t)(b * IN_C + c)) * NPIX
                                              + (y0 + y) * WWID + x4 * 4);
            unsigned short bf0 = f2bf(v.x), bf1 = f2bf(v.y), bf2 = f2bf(v.z), bf3 = f2bf(v.w);
            const int ppb = (y * WWID + x4 * 4) ^ (((c >> 3) & 15) << 2);
            uint2 pk;
            pk.x = (unsigned)bf0 | ((unsigned)bf1 << 16);
            pk.y = (unsigned)bf2 | ((unsigned)bf3 << 16);
            *(uint2*)&tile[c * 128 + ppb] = pk;
        }
        __syncthreads();

        #pragma unroll
        for (int it = 0; it < 7; it++) {
            const int ch = it * 256 + t;
            const int oct = ch & 15;
            const int pp = ch >> 4;
            const int sw = oct << 2;
            ushort8 v;
            #pragma unroll
            for (int i = 0; i < 8; i++)
                v[i] = tile[(oct * 8 + i) * 128 + (pp ^ sw)];
            const int y2 = (pp >= WWID) ? 1 : 0;
            const int xg = pp - y2 * WWID;
            const size_t hp = (size_t)b * HPIX + (y0 + y2 + 1) * HALO + (xg + 1);
            *(ushort8*)&Xt[hp * 128 + oct * 8] = v;
        }

        if (t < 64) {   // halo columns xx=0,57 for this block's two rows
            const int pi = t >> 4, oct = t & 15;
            const int yy = y0 + 1 + (pi >> 1);
            const int xx = (pi & 1) * 57;
            *(ushort8*)&Xt[((size_t)b * HPIX + yy * HALO + xx) * 128 + oct * 8] =
                (ushort8){0, 0, 0, 0, 0, 0, 0, 0};
        }
        if (yt == 0 || yt == 27) {   // halo rows yy=0 / 57
            const int yy = (yt == 0) ? 0 : 57;
            #pragma unroll
            for (int it = 0; it < 4; it++) {
                const int ch = it * 256 + t;
                if (ch < 928) {
                    const int xx = ch >> 4, oct = ch & 15;
                    *(ushort8*)&Xt[((size_t)b * HPIX + yy * HALO + xx) * 128 + oct * 8] =
                        (ushort8){0, 0, 0, 0, 0, 0, 0, 0};
                }
            }
        }
        return;
    }
    // ---- probs: Pws[b][p][8] = softmax(Alpha)[.,p] or one-hot(mask[p]) ----
    {
        const int idx = blk - 1376;          // 0..103
        const int b  = idx / 13;
        const int pt = idx - b * 13;
        const int p  = pt * 256 + t;
        if (p >= PPAD) return;
        float pr[8] = {0, 0, 0, 0, 0, 0, 0, 0};
        if (p < NPIX) {
            if (use_alpha[0]) {
                float m = -1e30f;
                #pragma unroll
                for (int g = 0; g < 8; g++) {
                    pr[g] = Alpha[((size_t)(b * NG + g)) * NPIX + p];
                    m = fmaxf(m, pr[g]);
                }
                float sum = 0.f;
                #pragma unroll
                for (int g = 0; g < 8; g++) { pr[g] = expf(pr[g] - m); sum += pr[g]; }
                const float inv = 1.f / sum;
                #pragma unroll
                for (int g = 0; g < 8; g++) pr[g] *= inv;
            } else {
                const int mg = mask[(size_t)b * NPIX + p];
                #pragma unroll
                for (int g = 0; g < 8; g++) pr[g] = (g == mg) ? 1.f : 0.f;
            }
        }
        float* dst = Pws + ((size_t)b * PPAD + p) * 8;
        *(f32x4*)dst = (f32x4){pr[0], pr[1], pr[2], pr[3]};
        *(f32x4*)(dst + 4) = (f32x4){pr[4], pr[5], pr[6], pr[7]};
    }
}

// ---------- 2) main GEMM + factored routing/blend epilogue ----------
// Main loop identical to R4 (79us): 36 BK=32 stages in 18 pairs, 4 B-buffers,
// one barrier per pair, ALL VMEM for pair p+1 at pair-top (afc/afn rotation).
// Epilogue: cooperative rsh (Bsh-reuse LDS) + branch-free blend from Pws.
__global__ __launch_bounds__(256) void gemm_kernel(const unsigned short* __restrict__ Apack,
                                                   const unsigned short* __restrict__ Xt,
                                                   const float* __restrict__ Pws,
                                                   const float* __restrict__ xse,
                                                   const float* __restrict__ rw,
                                                   const float* __restrict__ rb,
                                                   const float* __restrict__ bias,
                                                   float* __restrict__ out) {
    __shared__ __align__(16) unsigned short Bsh[4][512 * 8];   // 4 x 8 KB
    const int tid = threadIdx.x;
    const int wv = tid >> 6, ln = tid & 63;
    const int lq = ln >> 4, lr = ln & 15;
    const int wrow = wv >> 1, wcol = wv & 1;

    const int lid = blockIdx.x;            // 0..3199
    const int b   = lid & 7;               // XCD = b
    const int sl  = lid >> 3;              // 0..399
    const int mt  = sl & 15;               // 16 M-tiles of 64 rows
    const int nt  = sl >> 4;               // 0..24

    f32x4 acc[2][4];
    #pragma unroll
    for (int i = 0; i < 2; i++)
        #pragma unroll
        for (int j = 0; j < 4; j++) acc[i][j] = (f32x4){0.f, 0.f, 0.f, 0.f};

    // B staging: chunk (r, slot js) holds octet q = js ^ (r&3) ^ ((r>>2)&3)
    const int js = tid & 3;
    const int r0 = tid >> 2,  q0 = js ^ (r0 & 3) ^ ((r0 >> 2) & 3);
    const int r1 = r0 + 64,   q1 = js ^ (r1 & 3) ^ ((r1 >> 2) & 3);
    const int p0 = min(nt * 128 + r0, NPIX - 1);
    const int p1 = min(nt * 128 + r1, NPIX - 1);
    const int y0p = p0 / WWID, x0p = p0 - y0p * WWID;
    const int y1p = p1 / WWID, x1p = p1 - y1p * WWID;
    const unsigned short* gb0 = Xt + ((size_t)b * HPIX + y0p * HALO + x0p) * 128 + q0 * 8;
    const unsigned short* gb1 = Xt + ((size_t)b * HPIX + y1p * HALO + x1p) * 128 + q1 * 8;
    unsigned short* lbA[4];   // per-buffer LDS target for chunk0 (chunk1 = +256*8)
    #pragma unroll
    for (int i = 0; i < 4; i++) lbA[i] = &Bsh[i][(wv * 64) * 8];

    // A fragment-linear bases: m16 = mt*4 + wrow*2 + tm, tm in 0..1
    const unsigned short* gaw[2];
    #pragma unroll
    for (int tm = 0; tm < 2; tm++) {
        const int m16 = mt * 4 + wrow * 2 + tm;
        gaw[tm] = Apack + ((size_t)m16 * 36 * 64 + ln) * 8;
    }

    // frag-read slot swizzle: j' = lq ^ (lr&3) ^ ((lr>>2)&3)
    const int jj = lq ^ (lr & 3) ^ ((lr >> 2) & 3);

    // prologue: tiles 0,1 -> buf0,buf1 (stage1 offB = 32); afc = stages 0,1
    cp16(gb0, lbA[0]); cp16(gb1, lbA[0] + 256 * 8);
    cp16(gb0 + 32, lbA[1]); cp16(gb1 + 32, lbA[1] + 256 * 8);
    short8 afc[2][2], afn[2][2];
    #pragma unroll
    for (int tm = 0; tm < 2; tm++) afc[0][tm] = *(const short8*)(gaw[tm]);
    #pragma unroll
    for (int tm = 0; tm < 2; tm++) afc[1][tm] = *(const short8*)(gaw[tm] + 512);

    #pragma unroll 1
    for (int it = 0; it < 9; it++) {
        // ================= pair 2*it (even): buffers 0,1; uses afc ===========
        __syncthreads();                   // stages 4it,4it+1 + afc ready
        {
            const int st2 = it * 4 + 2, st3 = it * 4 + 3;
            const int nk2 = st2 * 32, s2 = nk2 >> 7;
            const int kh2 = s2 / 3, kw2 = s2 - 3 * kh2;
            const int off2 = (kh2 * HALO + kw2) * 128 + (nk2 & 127);
            const int nk3 = st3 * 32, s3 = nk3 >> 7;
            const int kh3 = s3 / 3, kw3 = s3 - 3 * kh3;
            const int off3 = (kh3 * HALO + kw3) * 128 + (nk3 & 127);
            cp16(gb0 + off2, lbA[2]); cp16(gb1 + off2, lbA[2] + 256 * 8);
            cp16(gb0 + off3, lbA[3]); cp16(gb1 + off3, lbA[3] + 256 * 8);
            #pragma unroll
            for (int tm = 0; tm < 2; tm++)
                afn[0][tm] = *(const short8*)(gaw[tm] + (size_t)st2 * 512);
            #pragma unroll
            for (int tm = 0; tm < 2; tm++)
                afn[1][tm] = *(const short8*)(gaw[tm] + (size_t)st3 * 512);
            __builtin_amdgcn_sched_barrier(0);   // keep VMEM issue at pair-top

            // stage 4it: buffer 0, afc[0]
            {
                short8 bfr[4];
                #pragma unroll
                for (int tn = 0; tn < 4; tn++) {
                    const int row = wcol * 64 + tn * 16 + lr;
                    bfr[tn] = *(const short8*)&Bsh[0][(row * 4 + jj) * 8];
                }
                #pragma unroll
                for (int tm = 0; tm < 2; tm++)
                    #pragma unroll
                    for (int tn = 0; tn < 4; tn++)
                        acc[tm][tn] = __builtin_amdgcn_mfma_f32_16x16x32_bf16(
                            afc[0][tm], bfr[tn], acc[tm][tn], 0, 0, 0);
            }
            // stage 4it+1: buffer 1, afc[1]
            {
                short8 bfr[4];
                #pragma unroll
                for (int tn = 0; tn < 4; tn++) {
                    const int row = wcol * 64 + tn * 16 + lr;
                    bfr[tn] = *(const short8*)&Bsh[1][(row * 4 + jj) * 8];
                }
                #pragma unroll
                for (int tm = 0; tm < 2; tm++)
                    #pragma unroll
                    for (int tn = 0; tn < 4; tn++)
                        acc[tm][tn] = __builtin_amdgcn_mfma_f32_16x16x32_bf16(
                            afc[1][tm], bfr[tn], acc[tm][tn], 0, 0, 0);
            }
        }
        // ================= pair 2*it+1 (odd): buffers 2,3; uses afn ==========
        __syncthreads();                   // stages 4it+2,4it+3 + afn ready
        {
            if (it < 8) {
                const int st2 = it * 4 + 4, st3 = it * 4 + 5;
                const int nk2 = st2 * 32, s2 = nk2 >> 7;
                const int kh2 = s2 / 3, kw2 = s2 - 3 * kh2;
                const int off2 = (kh2 * HALO + kw2) * 128 + (nk2 & 127);
                const int nk3 = st3 * 32, s3 = nk3 >> 7;
                const int kh3 = s3 / 3, kw3 = s3 - 3 * kh3;
                const int off3 = (kh3 * HALO + kw3) * 128 + (nk3 & 127);
                cp16(gb0 + off2, lbA[0]); cp16(gb1 + off2, lbA[0] + 256 * 8);
                cp16(gb0 + off3, lbA[1]); cp16(gb1 + off3, lbA[1] + 256 * 8);
                #pragma unroll
                for (int tm = 0; tm < 2; tm++)
                    afc[0][tm] = *(const short8*)(gaw[tm] + (size_t)st2 * 512);
                #pragma unroll
                for (int tm = 0; tm < 2; tm++)
                    afc[1][tm] = *(const short8*)(gaw[tm] + (size_t)st3 * 512);
            }
            __builtin_amdgcn_sched_barrier(0);   // keep VMEM issue at pair-top

            // stage 4it+2: buffer 2, afn[0]
            {
                short8 bfr[4];
                #pragma unroll
                for (int tn = 0; tn < 4; tn++) {
                    const int row = wcol * 64 + tn * 16 + lr;
                    bfr[tn] = *(const short8*)&Bsh[2][(row * 4 + jj) * 8];
                }
                #pragma unroll
                for (int tm = 0; tm < 2; tm++)
                    #pragma unroll
                    for (int tn = 0; tn < 4; tn++)
                        acc[tm][tn] = __builtin_amdgcn_mfma_f32_16x16x32_bf16(
                            afn[0][tm], bfr[tn], acc[tm][tn], 0, 0, 0);
            }
            // stage 4it+3: buffer 3, afn[1]
            {
                short8 bfr[4];
                #pragma unroll
                for (int tn = 0; tn < 4; tn++) {
                    const int row = wcol * 64 + tn * 16 + lr;
                    bfr[tn] = *(const short8*)&Bsh[3][(row * 4 + jj) * 8];
                }
                #pragma unroll
                for (int tm = 0; tm < 2; tm++)
                    #pragma unroll
                    for (int tn = 0; tn < 4; tn++)
                        acc[tm][tn] = __builtin_amdgcn_mfma_f32_16x16x32_bf16(
                            afn[1][tm], bfr[tn], acc[tm][tn], 0, 0, 0);
            }
        }
    }

    // ---------- factored routing epilogue (low-VGPR, branch-free) ----------
    // rsh[t] = 0.25/(1+exp(-(rb[t] + xse[b,:].rw[t,:]))), computed
    // cooperatively: thread tid handles quarter (tid&3) of neuron (tid>>2),
    // coalesced f32x4 rw reads, 2x shfl_xor fold, write into reused Bsh LDS.
    __syncthreads();                       // all waves done with Bsh
    float* rshL = (float*)&Bsh[0][0];      // 64 floats (256 B) reuse
    {
        const int tq = tid >> 2, qq = tid & 3;
        const float* rwr = rw + tq * IN_C + qq * 32;
        const float* xsb = xse + b * IN_C + qq * 32;
        float partial = 0.f;
        #pragma unroll
        for (int c = 0; c < 32; c += 4) {
            const f32x4 wvv = *(const f32x4*)&rwr[c];
            const f32x4 xvv = *(const f32x4*)&xsb[c];
            partial += xvv.x * wvv.x + xvv.y * wvv.y + xvv.z * wvv.z + xvv.w * wvv.w;
        }
        partial += __shfl_xor(partial, 1);
        partial += __shfl_xor(partial, 2);
        if (qq == 0)
            rshL[tq] = 0.25f / (1.0f + expf(-(partial + rb[tq])));   // 2*sigmoid/8
    }
    __syncthreads();                       // rshL visible to all

    // blend: sj = sum_g P[g](p) * rshL[g*8+j0..+3]; j0 = (lq&1)*4
    const int j0 = (lq & 1) * 4;
    const int oo = lq >> 1;
    #pragma unroll
    for (int tn = 0; tn < 4; tn++) {
        const int p = nt * 128 + wcol * 64 + tn * 16 + lr;   // < PPAD always
        const float* Pp = Pws + ((size_t)b * PPAD + p) * 8;
        const f32x4 pA = *(const f32x4*)Pp;
        const f32x4 pB = *(const f32x4*)(Pp + 4);
        f32x4 sj = (f32x4){0.f, 0.f, 0.f, 0.f};
        {   // broadcast ds_read_b128 per g, conflict-free
            const f32x4 r0v = *(const f32x4*)&rshL[0 * 8 + j0];
            const f32x4 r1v = *(const f32x4*)&rshL[1 * 8 + j0];
            const f32x4 r2v = *(const f32x4*)&rshL[2 * 8 + j0];
            const f32x4 r3v = *(const f32x4*)&rshL[3 * 8 + j0];
            sj += pA.x * r0v + pA.y * r1v + pA.z * r2v + pA.w * r3v;
            const f32x4 r4v = *(const f32x4*)&rshL[4 * 8 + j0];
            const f32x4 r5v = *(const f32x4*)&rshL[5 * 8 + j0];
            const f32x4 r6v = *(const f32x4*)&rshL[6 * 8 + j0];
            const f32x4 r7v = *(const f32x4*)&rshL[7 * 8 + j0];
            sj += pB.x * r4v + pB.y * r5v + pB.z * r6v + pB.w * r7v;
        }
        #pragma unroll
        for (int tm = 0; tm < 2; tm++) {
            const int o = mt * 8 + wrow * 4 + tm * 2 + oo;
            const f32x4 a = acc[tm][tn];
            float part = a.x * sj.x + a.y * sj.y + a.z * sj.z + a.w * sj.w;
            float tot = part + __shfl_xor(part, 16);
            if ((lq & 1) == 0 && p < NPIX)
                out[((size_t)b * OUT_C + o) * NPIX + p] = tot + bias[o];
        }
    }
}

extern "C" void kernel_launch(void* const* d_in, const int* in_sizes, int n_in,
                              void* d_out, int out_size, void* d_ws, size_t ws_size,
                              hipStream_t stream) {
    const float* inputs = (const float*)d_in[0];
    const int*   mask   = (const int*)d_in[1];
    const float* Alpha  = (const float*)d_in[2];
    const float* wtmpl  = (const float*)d_in[3];
    const float* rw     = (const float*)d_in[4];
    const float* rb     = (const float*)d_in[5];
    const float* bias   = (const float*)d_in[6];
    const int*   ua     = (const int*)d_in[7];
    float* out = (float*)d_out;

    char* ws = (char*)d_ws;
    unsigned short* Xt  = (unsigned short*)ws;                  // 8*3364*128*2 = 6,889,472
    unsigned short* Apk = (unsigned short*)(ws + 6889472);      // 1024*1152*2  = 2,359,296
    float*          Pws = (float*)(ws + 9248768);               // 8*3200*8*4   =   819,200
    float*          xse = (float*)(ws + 10067968);              // 1024*4

    prep_kernel<<<1480, 256, 0, stream>>>(inputs, wtmpl, Alpha, mask, ua, xse, Apk, Xt, Pws);
    gemm_kernel<<<3200, 256, 0, stream>>>(Apk, Xt, Pws, xse, rw, rb, bias, out);
}

// Round 13
// 158.665 us; speedup vs baseline: 1.4284x; 1.0998x over previous
//
#include <hip/hip_runtime.h>
#include <stdint.h>

#define IN_C   128
#define OUT_C  128
#define KTOT   1152      // IN_C*3*3
#define NG     8
#define NW     8
#define NB     8
#define HH     56
#define WWID   56
#define NPIX   3136
#define PPAD   3200
#define MTOT   1024      // OUT_C*NW
#define HALO   58        // 56 + zero border on each side
#define HPIX   (HALO*HALO)   // 3364

// R13: consolidation. R4 restored byte-for-byte (session best: gemm 79.0us,
// total 161.2us) after the complete falsification tree: occupancy x2 flat
// (R3), launch-bounds caps spill (R2/R5), all-global B issue-bound (R6),
// 32x32 tail pathology (R7), 256-tile VGPR cliff (R8), 8-phase barrier
// overhead (R1), epilogue fusion net-negative x3 (R10-R12: any fused
// epilogue perturbs main-loop codegen, slowing the WHOLE kernel uniformly).
// One free tweak: prep block-IDs remapped so slow tconv blocks dispatch
// FIRST (grid 1376 vs 1280 capacity -> 2nd generation = cheap transpose
// blocks only). Gemm sits at the 2-phase-structure ceiling; the 8-phase
// escape needs 8-wave 256^2 geometry this problem rejects.

typedef __attribute__((ext_vector_type(8))) short short8;
typedef __attribute__((ext_vector_type(8))) unsigned short ushort8;
typedef __attribute__((ext_vector_type(4))) float f32x4;

__device__ __forceinline__ unsigned short f2bf(float f) {
    unsigned u = __float_as_uint(f);
    u += 0x7FFF + ((u >> 16) & 1);          // round-to-nearest-even
    return (unsigned short)(u >> 16);
}

__device__ __forceinline__ void cp16(const unsigned short* g, unsigned short* l) {
    __builtin_amdgcn_global_load_lds(
        (const __attribute__((address_space(1))) unsigned int*)g,
        (__attribute__((address_space(3))) unsigned int*)l,
        16, 0, 0);
}

// ---------- 1) fused prep: tconv/pack (0..127) | gap (128..1151) | transpose (1152..1375) ----------
// tconv first: slow blocks lead the dispatch; the 96-block 2nd generation is
// cheap transpose blocks.
__global__ __launch_bounds__(256) void prep_kernel(const float* __restrict__ in,
                                                   const float* __restrict__ T,
                                                   float* __restrict__ xse,
                                                   unsigned short* __restrict__ Apack,
                                                   unsigned short* __restrict__ Xt) {
    __shared__ __align__(16) unsigned char smem[32768];   // 32 KB
    const int blk = blockIdx.x;
    const int t = threadIdx.x;

    if (blk < 128) {
        // ---- tconv+pack: block per o. T[o][k][j] slab -> bf16 LDS (18 KB) ->
        //      fragment-linear Apack[m16][kt][lq][lr][8e].
        unsigned short* lh = (unsigned short*)smem;  // 9216 bf16 = 18 KB
        const int o = blk;
        const float* To = T + (size_t)o * 9216;
        #pragma unroll
        for (int it = 0; it < 9; it++) {
            const int f = it * 256 + t;              // 0..2303 float4 units
            const float4 v = ((const float4*)To)[f];
            ushort4 h;
            h.x = f2bf(v.x); h.y = f2bf(v.y); h.z = f2bf(v.z); h.w = f2bf(v.w);
            *(ushort4*)&lh[f * 4] = h;
        }
        __syncthreads();
        const int m16b = o >> 1;
        const int lrb = (o & 1) * 8;
        #pragma unroll
        for (int it = 0; it < 5; it++) {
            const int ch = it * 256 + t;             // 0..1151: ch = kc*8 + j
            if (ch < 1152) {
                const int j = ch & 7, kc = ch >> 3;  // kc = k-octet 0..143
                const int s = kc >> 4, c0 = (kc & 15) << 3;
                const int kt = kc >> 2, lq = kc & 3;
                ushort8 v;
                #pragma unroll
                for (int i = 0; i < 8; i++)
                    v[i] = lh[((c0 + i) * 9 + s) * 8 + j];
                const size_t off = ((((size_t)m16b * 36 + kt) * 4 + lq) * 16 + lrb + j) * 8;
                *(ushort8*)&Apack[off] = v;
            }
        }
        return;
    }
    if (blk < 1152) {
        // ---- global average pool: xse[b,c] ----
        const int id = blk - 128;                    // 0..1023 = b*IN_C + c
        const float* src = in + (size_t)id * NPIX;
        float s = 0.f;
        for (int i = t; i < NPIX / 4; i += 256) {
            float4 v = ((const float4*)src)[i];
            s += v.x + v.y + v.z + v.w;
        }
        #pragma unroll
        for (int off = 32; off; off >>= 1) s += __shfl_down(s, off);
        float* ws4 = (float*)smem;
        if ((t & 63) == 0) ws4[t >> 6] = s;
        __syncthreads();
        if (t == 0)
            xse[id] = (ws4[0] + ws4[1] + ws4[2] + ws4[3]) * (1.0f / (float)NPIX);
        return;
    }
    // ---- transpose: in[b][c][y][x] fp32 -> Xt[b][(y+1)*58+(x+1)][c] bf16, zero halo ----
    unsigned short* tile = (unsigned short*)smem;    // 32 KB, [c][pix 0..112)
    const int idx = blk - 1152;                      // 0..223
    const int yt = idx % 28;
    const int b  = idx / 28;
    const int y0 = yt * 2;

    #pragma unroll
    for (int it = 0; it < 14; it++) {
        const int f = it * 256 + t;
        const int c = f / 28;
        const int rem = f - c * 28;
        const int y = rem / 14;
        const int x4 = rem - y * 14;
        const float4 v = *(const float4*)(in + ((size_t)(b * IN_C + c)) * NPIX
                                          + (y0 + y) * WWID + x4 * 4);
        unsigned short bf0 = f2bf(v.x), bf1 = f2bf(v.y), bf2 = f2bf(v.z), bf3 = f2bf(v.w);
        const int ppb = (y * WWID + x4 * 4) ^ (((c >> 3) & 15) << 2);
        uint2 pk;
        pk.x = (unsigned)bf0 | ((unsigned)bf1 << 16);
        pk.y = (unsigned)bf2 | ((unsigned)bf3 << 16);
        *(uint2*)&tile[c * 128 + ppb] = pk;
    }
    __syncthreads();

    #pragma unroll
    for (int it = 0; it < 7; it++) {
        const int ch = it * 256 + t;
        const int oct = ch & 15;
        const int pp = ch >> 4;
        const int sw = oct << 2;
        ushort8 v;
        #pragma unroll
        for (int i = 0; i < 8; i++)
            v[i] = tile[(oct * 8 + i) * 128 + (pp ^ sw)];
        const int y2 = (pp >= WWID) ? 1 : 0;
        const int xg = pp - y2 * WWID;
        const size_t hp = (size_t)b * HPIX + (y0 + y2 + 1) * HALO + (xg + 1);
        *(ushort8*)&Xt[hp * 128 + oct * 8] = v;
    }

    if (t < 64) {   // halo columns xx=0,57 for this block's two rows
        const int pi = t >> 4, oct = t & 15;
        const int yy = y0 + 1 + (pi >> 1);
        const int xx = (pi & 1) * 57;
        *(ushort8*)&Xt[((size_t)b * HPIX + yy * HALO + xx) * 128 + oct * 8] =
            (ushort8){0, 0, 0, 0, 0, 0, 0, 0};
    }
    if (yt == 0 || yt == 27) {   // halo rows yy=0 / 57
        const int yy = (yt == 0) ? 0 : 57;
        #pragma unroll
        for (int it = 0; it < 4; it++) {
            const int ch = it * 256 + t;
            if (ch < 928) {
                const int xx = ch >> 4, oct = ch & 15;
                *(ushort8*)&Xt[((size_t)b * HPIX + yy * HALO + xx) * 128 + oct * 8] =
                    (ushort8){0, 0, 0, 0, 0, 0, 0, 0};
            }
        }
    }
}

// ---------- 2) s_kernel (routing fused): s[b][p][j] = sum_g probs[b,g,p] * r[b,g*8+j] ----------
__global__ __launch_bounds__(256) void s_kernel(const float* __restrict__ Alpha,
                                                const int* __restrict__ mask,
                                                const float* __restrict__ xse,
                                                const float* __restrict__ rw,
                                                const float* __restrict__ rb,
                                                const int* __restrict__ use_alpha,
                                                float* __restrict__ Sws) {
    const int b = blockIdx.y;
    const int t = threadIdx.x;
    const int p = blockIdx.x * 256 + t;
    __shared__ float xs[IN_C];
    __shared__ float rsh[64];
    if (t < IN_C) xs[t] = xse[b * IN_C + t];
    __syncthreads();
    if (t < 64) {
        float acc = rb[t];
        #pragma unroll 8
        for (int c = 0; c < IN_C; c++) acc += xs[c] * rw[t * IN_C + c];
        rsh[t] = 0.25f / (1.0f + expf(-acc));        // 2*sigmoid/8
    }
    __syncthreads();
    if (p >= PPAD) return;
    float sj[8] = {0, 0, 0, 0, 0, 0, 0, 0};
    if (p < NPIX) {
        float pr[8];
        if (use_alpha[0]) {
            float a[8], m = -1e30f;
            #pragma unroll
            for (int g = 0; g < 8; g++) {
                a[g] = Alpha[((size_t)(b * NG + g)) * NPIX + p];
                m = fmaxf(m, a[g]);
            }
            float sum = 0.f;
            #pragma unroll
            for (int g = 0; g < 8; g++) { pr[g] = expf(a[g] - m); sum += pr[g]; }
            float inv = 1.f / sum;
            #pragma unroll
            for (int g = 0; g < 8; g++) pr[g] *= inv;
        } else {
            int mg = mask[(size_t)b * NPIX + p];
            #pragma unroll
            for (int g = 0; g < 8; g++) pr[g] = (g == mg) ? 1.f : 0.f;
        }
        #pragma unroll
        for (int g = 0; g < 8; g++)
            #pragma unroll
            for (int j = 0; j < 8; j++) sj[j] += pr[g] * rsh[g * 8 + j];
    }
    float* dst = Sws + ((size_t)b * PPAD + p) * 8;
    *(f32x4*)dst = (f32x4){sj[0], sj[1], sj[2], sj[3]};
    *(f32x4*)(dst + 4) = (f32x4){sj[4], sj[5], sj[6], sj[7]};
}

// ---------- 3) main GEMM + blend epilogue ----------
// 36 BK=32 stages in 18 pairs (unrolled 2 pairs/iter): 4 B-buffers, one barrier
// per pair. ALL VMEM for pair p+1 (4 cp16 + 4 A-frag loads) issued at top of
// pair p (afc/afn rotation), sched_barrier(0) pins the cluster.
// M-tile = 64 rows, N-tile = 128 px. Grid 3200. (R4, 79us verified.)
__global__ __launch_bounds__(256) void gemm_kernel(const unsigned short* __restrict__ Apack,
                                                   const unsigned short* __restrict__ Xt,
                                                   const float* __restrict__ Sws,
                                                   const float* __restrict__ bias,
                                                   float* __restrict__ out) {
    __shared__ __align__(16) unsigned short Bsh[4][512 * 8];   // 4 x 8 KB
    const int tid = threadIdx.x;
    const int wv = tid >> 6, ln = tid & 63;
    const int lq = ln >> 4, lr = ln & 15;
    const int wrow = wv >> 1, wcol = wv & 1;

    const int lid = blockIdx.x;            // 0..3199
    const int b   = lid & 7;               // XCD = b
    const int sl  = lid >> 3;              // 0..399
    const int mt  = sl & 15;               // 16 M-tiles of 64 rows
    const int nt  = sl >> 4;               // 0..24

    f32x4 acc[2][4];
    #pragma unroll
    for (int i = 0; i < 2; i++)
        #pragma unroll
        for (int j = 0; j < 4; j++) acc[i][j] = (f32x4){0.f, 0.f, 0.f, 0.f};

    // B staging: chunk (r, slot js) holds octet q = js ^ (r&3) ^ ((r>>2)&3)
    const int js = tid & 3;
    const int r0 = tid >> 2,  q0 = js ^ (r0 & 3) ^ ((r0 >> 2) & 3);
    const int r1 = r0 + 64,   q1 = js ^ (r1 & 3) ^ ((r1 >> 2) & 3);
    const int p0 = min(nt * 128 + r0, NPIX - 1);
    const int p1 = min(nt * 128 + r1, NPIX - 1);
    const int y0p = p0 / WWID, x0p = p0 - y0p * WWID;
    const int y1p = p1 / WWID, x1p = p1 - y1p * WWID;
    const unsigned short* gb0 = Xt + ((size_t)b * HPIX + y0p * HALO + x0p) * 128 + q0 * 8;
    const unsigned short* gb1 = Xt + ((size_t)b * HPIX + y1p * HALO + x1p) * 128 + q1 * 8;
    unsigned short* lbA[4];   // per-buffer LDS target for chunk0 (chunk1 = +256*8)
    #pragma unroll
    for (int i = 0; i < 4; i++) lbA[i] = &Bsh[i][(wv * 64) * 8];

    // A fragment-linear bases: m16 = mt*4 + wrow*2 + tm, tm in 0..1
    const unsigned short* gaw[2];
    #pragma unroll
    for (int tm = 0; tm < 2; tm++) {
        const int m16 = mt * 4 + wrow * 2 + tm;
        gaw[tm] = Apack + ((size_t)m16 * 36 * 64 + ln) * 8;
    }

    // frag-read slot swizzle: j' = lq ^ (lr&3) ^ ((lr>>2)&3)
    const int jj = lq ^ (lr & 3) ^ ((lr >> 2) & 3);

    // prologue: tiles 0,1 -> buf0,buf1 (stage1 offB = 32); afc = stages 0,1
    cp16(gb0, lbA[0]); cp16(gb1, lbA[0] + 256 * 8);
    cp16(gb0 + 32, lbA[1]); cp16(gb1 + 32, lbA[1] + 256 * 8);
    short8 afc[2][2], afn[2][2];
    #pragma unroll
    for (int tm = 0; tm < 2; tm++) afc[0][tm] = *(const short8*)(gaw[tm]);
    #pragma unroll
    for (int tm = 0; tm < 2; tm++) afc[1][tm] = *(const short8*)(gaw[tm] + 512);

    #pragma unroll 1
    for (int it = 0; it < 9; it++) {
        // ================= pair 2*it (even): buffers 0,1; uses afc ===========
        __syncthreads();                   // stages 4it,4it+1 + afc ready
        {
            const int st2 = it * 4 + 2, st3 = it * 4 + 3;
            const int nk2 = st2 * 32, s2 = nk2 >> 7;
            const int kh2 = s2 / 3, kw2 = s2 - 3 * kh2;
            const int off2 = (kh2 * HALO + kw2) * 128 + (nk2 & 127);
            const int nk3 = st3 * 32, s3 = nk3 >> 7;
            const int kh3 = s3 / 3, kw3 = s3 - 3 * kh3;
            const int off3 = (kh3 * HALO + kw3) * 128 + (nk3 & 127);
            cp16(gb0 + off2, lbA[2]); cp16(gb1 + off2, lbA[2] + 256 * 8);
            cp16(gb0 + off3, lbA[3]); cp16(gb1 + off3, lbA[3] + 256 * 8);
            #pragma unroll
            for (int tm = 0; tm < 2; tm++)
                afn[0][tm] = *(const short8*)(gaw[tm] + (size_t)st2 * 512);
            #pragma unroll
            for (int tm = 0; tm < 2; tm++)
                afn[1][tm] = *(const short8*)(gaw[tm] + (size_t)st3 * 512);
            __builtin_amdgcn_sched_barrier(0);   // keep VMEM issue at pair-top

            // stage 4it: buffer 0, afc[0]
            {
                short8 bfr[4];
                #pragma unroll
                for (int tn = 0; tn < 4; tn++) {
                    const int row = wcol * 64 + tn * 16 + lr;
                    bfr[tn] = *(const short8*)&Bsh[0][(row * 4 + jj) * 8];
                }
                #pragma unroll
                for (int tm = 0; tm < 2; tm++)
                    #pragma unroll
                    for (int tn = 0; tn < 4; tn++)
                        acc[tm][tn] = __builtin_amdgcn_mfma_f32_16x16x32_bf16(
                            afc[0][tm], bfr[tn], acc[tm][tn], 0, 0, 0);
            }
            // stage 4it+1: buffer 1, afc[1]
            {
                short8 bfr[4];
                #pragma unroll
                for (int tn = 0; tn < 4; tn++) {
                    const int row = wcol * 64 + tn * 16 + lr;
                    bfr[tn] = *(const short8*)&Bsh[1][(row * 4 + jj) * 8];
                }
                #pragma unroll
                for (int tm = 0; tm < 2; tm++)
                    #pragma unroll
                    for (int tn = 0; tn < 4; tn++)
                        acc[tm][tn] = __builtin_amdgcn_mfma_f32_16x16x32_bf16(
                            afc[1][tm], bfr[tn], acc[tm][tn], 0, 0, 0);
            }
        }
        // ================= pair 2*it+1 (odd): buffers 2,3; uses afn ==========
        __syncthreads();                   // stages 4it+2,4it+3 + afn ready
        {
            if (it < 8) {
                const int st2 = it * 4 + 4, st3 = it * 4 + 5;
                const int nk2 = st2 * 32, s2 = nk2 >> 7;
                const int kh2 = s2 / 3, kw2 = s2 - 3 * kh2;
                const int off2 = (kh2 * HALO + kw2) * 128 + (nk2 & 127);
                const int nk3 = st3 * 32, s3 = nk3 >> 7;
                const int kh3 = s3 / 3, kw3 = s3 - 3 * kh3;
                const int off3 = (kh3 * HALO + kw3) * 128 + (nk3 & 127);
                cp16(gb0 + off2, lbA[0]); cp16(gb1 + off2, lbA[0] + 256 * 8);
                cp16(gb0 + off3, lbA[1]); cp16(gb1 + off3, lbA[1] + 256 * 8);
                #pragma unroll
                for (int tm = 0; tm < 2; tm++)
                    afc[0][tm] = *(const short8*)(gaw[tm] + (size_t)st2 * 512);
                #pragma unroll
                for (int tm = 0; tm < 2; tm++)
                    afc[1][tm] = *(const short8*)(gaw[tm] + (size_t)st3 * 512);
            }
            __builtin_amdgcn_sched_barrier(0);   // keep VMEM issue at pair-top

            // stage 4it+2: buffer 2, afn[0]
            {
                short8 bfr[4];
                #pragma unroll
                for (int tn = 0; tn < 4; tn++) {
                    const int row = wcol * 64 + tn * 16 + lr;
                    bfr[tn] = *(const short8*)&Bsh[2][(row * 4 + jj) * 8];
                }
                #pragma unroll
                for (int tm = 0; tm < 2; tm++)
                    #pragma unroll
                    for (int tn = 0; tn < 4; tn++)
                        acc[tm][tn] = __builtin_amdgcn_mfma_f32_16x16x32_bf16(
                            afn[0][tm], bfr[tn], acc[tm][tn], 0, 0, 0);
            }
            // stage 4it+3: buffer 3, afn[1]
            {
                short8 bfr[4];
                #pragma unroll
                for (int tn = 0; tn < 4; tn++) {
                    const int row = wcol * 64 + tn * 16 + lr;
                    bfr[tn] = *(const short8*)&Bsh[3][(row * 4 + jj) * 8];
                }
                #pragma unroll
                for (int tm = 0; tm < 2; tm++)
                    #pragma unroll
                    for (int tn = 0; tn < 4; tn++)
                        acc[tm][tn] = __builtin_amdgcn_mfma_f32_16x16x32_bf16(
                            afn[1][tm], bfr[tn], acc[tm][tn], 0, 0, 0);
            }
        }
    }

    // epilogue: row r = m16*16 + lq*4 + reg -> o = r>>3 = m16*2 + (lq>>1), j = (lq&1)*4 + reg
    const int j0 = (lq & 1) * 4;
    const int oo = lq >> 1;
    #pragma unroll
    for (int tm = 0; tm < 2; tm++) {
        const int o = mt * 8 + wrow * 4 + tm * 2 + oo;
        const float bo = bias[o];
        #pragma unroll
        for (int tn = 0; tn < 4; tn++) {
            const int p = nt * 128 + wcol * 64 + tn * 16 + lr;
            const f32x4 sv = *(const f32x4*)&Sws[((size_t)b * PPAD + p) * 8 + j0];
            const f32x4 a = acc[tm][tn];
            float part = a.x * sv.x + a.y * sv.y + a.z * sv.z + a.w * sv.w;
            float tot = part + __shfl_xor(part, 16);
            if ((lq & 1) == 0 && p < NPIX)
                out[((size_t)b * OUT_C + o) * NPIX + p] = tot + bo;
        }
    }
}

extern "C" void kernel_launch(void* const* d_in, const int* in_sizes, int n_in,
                              void* d_out, int out_size, void* d_ws, size_t ws_size,
                              hipStream_t stream) {
    const float* inputs = (const float*)d_in[0];
    const int*   mask   = (const int*)d_in[1];
    const float* Alpha  = (const float*)d_in[2];
    const float* wtmpl  = (const float*)d_in[3];
    const float* rw     = (const float*)d_in[4];
    const float* rb     = (const float*)d_in[5];
    const float* bias   = (const float*)d_in[6];
    const int*   ua     = (const int*)d_in[7];
    float* out = (float*)d_out;

    char* ws = (char*)d_ws;
    unsigned short* Xt  = (unsigned short*)ws;                  // 8*3364*128*2 = 6,889,472
    unsigned short* Apk = (unsigned short*)(ws + 6889472);      // 1024*1152*2  = 2,359,296
    float*          Sws = (float*)(ws + 9248768);               // 8*3200*8*4   =   819,200
    float*          xse = (float*)(ws + 10067968);              // 1024*4

    prep_kernel<<<1376, 256, 0, stream>>>(inputs, wtmpl, xse, Apk, Xt);
    s_kernel<<<dim3(13, NB), 256, 0, stream>>>(Alpha, mask, xse, rw, rb, ua, Sws);
    gemm_kernel<<<3200, 256, 0, stream>>>(Apk, Xt, Sws, bias, out);
}